// Round 1
// baseline (1275.455 us; speedup 1.0000x reference)
//
#include <hip/hip_runtime.h>

#define NUM_PROCS 16
#define PROC_DIM 8
#define SPATIAL_DIM 3
#define ROW_DIM (PROC_DIM + SPATIAL_DIM)   // 11
#define BLOCK 128
#define RPT 4                               // rows per thread (consecutive quad)
#define ROWS_PER_BLOCK (BLOCK * RPT)        // 512; 8,000,000 / 512 = 15625 exactly
#define SPROC_STRIDE 12                     // pad 8->12 dwords: 48 B rows, keeps
                                            // ds_read_b128 16B-aligned and spreads the
                                            // 16 pids across bank pairs (~2-way, free)

typedef float v4f __attribute__((ext_vector_type(4)));
typedef int   v4i __attribute__((ext_vector_type(4)));

__global__ __launch_bounds__(BLOCK) void gather_concat_kernel(
    const float* __restrict__ proc_pos,     // [16, 8]
    const float* __restrict__ locs_sp,      // [500000, 3]
    const int*   __restrict__ process_ids,  // [NAUG]
    const int*   __restrict__ location_ids, // [NAUG]
    float* __restrict__ out,                // [NAUG, 11]
    int naug)
{
    // Only the tiny proc table lives in LDS now. The old full-row LDS staging tile
    // capped (waves/CU x gathers/lane) at ~57 via the LDS<->occupancy tradeoff;
    // dropping it is what buys gather MLP (the kernel is gather-LATENCY-bound:
    // 6 MB table > 4 MiB per-XCD L2 -> ~1/3 of lines come from L3 at ~600-900 cy).
    __shared__ float sproc[NUM_PROCS * SPROC_STRIDE];   // 768 B

    const int t = threadIdx.x;
    const int block_row0 = blockIdx.x * ROWS_PER_BLOCK;
    const bool full = (block_row0 + ROWS_PER_BLOCK <= naug);   // block-uniform

    // Stage proc table (128 valid dwords) with padded stride.
    if (t < NUM_PROCS * PROC_DIM) {
        sproc[(t >> 3) * SPROC_STRIDE + (t & 7)] = proc_pos[t];
    }

    const int r0 = block_row0 + RPT * t;

    if (full) {
        // 16 B/lane contiguous NT index loads (streamed once).
        v4i pid4 = __builtin_nontemporal_load((const v4i*)(process_ids + block_row0) + t);
        v4i lid4 = __builtin_nontemporal_load((const v4i*)(location_ids + block_row0) + t);

        // 4 independent scattered gathers per lane, all issued before the barrier:
        // this is the latency-bound resource; keep them in flight together.
        // (compiler merges each triple into one global_load_dwordx3, align 4)
        const float* l0 = locs_sp + (size_t)lid4.x * SPATIAL_DIM;
        const float* l1 = locs_sp + (size_t)lid4.y * SPATIAL_DIM;
        const float* l2 = locs_sp + (size_t)lid4.z * SPATIAL_DIM;
        const float* l3 = locs_sp + (size_t)lid4.w * SPATIAL_DIM;
        float a0 = l0[0], a1 = l0[1], a2 = l0[2];
        float b0 = l1[0], b1 = l1[1], b2 = l1[2];
        float c0 = l2[0], c1 = l2[1], c2 = l2[2];
        float e0 = l3[0], e1 = l3[1], e2 = l3[2];

        __syncthreads();   // sproc ready

        // Proc fragments: 2x ds_read_b128 per row from the padded table.
        // 16 distinct addrs among 64 lanes -> broadcast dedupe + stride-12 spread.
        const v4f* P0 = (const v4f*)(sproc + pid4.x * SPROC_STRIDE);
        const v4f* P1 = (const v4f*)(sproc + pid4.y * SPROC_STRIDE);
        const v4f* P2 = (const v4f*)(sproc + pid4.z * SPROC_STRIDE);
        const v4f* P3 = (const v4f*)(sproc + pid4.w * SPROC_STRIDE);
        v4f p0a = P0[0], p0b = P0[1];
        v4f p1a = P1[0], p1b = P1[1];
        v4f p2a = P2[0], p2b = P2[1];
        v4f p3a = P3[0], p3b = P3[1];

        // Pack 4 rows (44 floats) into 11 v4f. Per-thread region = 176 B and
        // (block_row0 + 4t)*44 is divisible by 16 -> every store is a 16B-aligned
        // global_store_dwordx4. All indices static -> pure register renaming,
        // no scratch (rule #20).
        v4f w0  = {p0a.x, p0a.y, p0a.z, p0a.w};
        v4f w1  = {p0b.x, p0b.y, p0b.z, p0b.w};
        v4f w2  = {a0,    a1,    a2,    p1a.x};
        v4f w3  = {p1a.y, p1a.z, p1a.w, p1b.x};
        v4f w4  = {p1b.y, p1b.z, p1b.w, b0   };
        v4f w5  = {b1,    b2,    p2a.x, p2a.y};
        v4f w6  = {p2a.z, p2a.w, p2b.x, p2b.y};
        v4f w7  = {p2b.z, p2b.w, c0,    c1   };
        v4f w8  = {c2,    p3a.x, p3a.y, p3a.z};
        v4f w9  = {p3a.w, p3b.x, p3b.y, p3b.z};
        v4f w10 = {p3b.w, e0,    e1,    e2   };

        // Direct NT stores from registers. Lane stride is 176 B so individual
        // instructions are scattered, but the 11-store sequence fully covers a
        // contiguous 11264 B window per wave -> L2 write-merge reassembles full
        // lines; HBM write bytes identical to the staged version. NT keeps the
        // write stream from evicting the locs_sp table out of L2.
        v4f* o = (v4f*)(out + (size_t)r0 * ROW_DIM);
        __builtin_nontemporal_store(w0,  o + 0);
        __builtin_nontemporal_store(w1,  o + 1);
        __builtin_nontemporal_store(w2,  o + 2);
        __builtin_nontemporal_store(w3,  o + 3);
        __builtin_nontemporal_store(w4,  o + 4);
        __builtin_nontemporal_store(w5,  o + 5);
        __builtin_nontemporal_store(w6,  o + 6);
        __builtin_nontemporal_store(w7,  o + 7);
        __builtin_nontemporal_store(w8,  o + 8);
        __builtin_nontemporal_store(w9,  o + 9);
        __builtin_nontemporal_store(w10, o + 10);
    } else {
        __syncthreads();   // sproc ready (block-uniform path, no divergence hazard)
        // generic tail block (not hit for NAUG = 8M)
        for (int k = 0; k < RPT; ++k) {
            const int r = r0 + k;
            if (r < naug) {
                const int pid = process_ids[r];
                const int lid = location_ids[r];
                const float* ps = sproc + pid * SPROC_STRIDE;
                const float* ls = locs_sp + (size_t)lid * SPATIAL_DIM;
                float* orow = out + (size_t)r * ROW_DIM;
                #pragma unroll
                for (int j = 0; j < PROC_DIM; ++j) orow[j] = ps[j];
                orow[8] = ls[0]; orow[9] = ls[1]; orow[10] = ls[2];
            }
        }
    }
}

extern "C" void kernel_launch(void* const* d_in, const int* in_sizes, int n_in,
                              void* d_out, int out_size, void* d_ws, size_t ws_size,
                              hipStream_t stream) {
    const float* proc_pos     = (const float*)d_in[0];
    const float* locs_sp      = (const float*)d_in[1];
    const int*   process_ids  = (const int*)d_in[2];
    const int*   location_ids = (const int*)d_in[3];
    float* out = (float*)d_out;

    const int naug = in_sizes[2];   // 8,000,000
    const int grid = (naug + ROWS_PER_BLOCK - 1) / ROWS_PER_BLOCK;

    gather_concat_kernel<<<grid, BLOCK, 0, stream>>>(
        proc_pos, locs_sp, process_ids, location_ids, out, naug);
}

// Round 2
// 461.237 us; speedup vs baseline: 2.7653x; 2.7653x over previous
//
#include <hip/hip_runtime.h>

#define NUM_PROCS 16
#define PROC_DIM 8
#define SPATIAL_DIM 3
#define ROW_DIM (PROC_DIM + SPATIAL_DIM)       // 11
#define BLOCK 256
#define WAVES_PB (BLOCK / 64)                  // 4 waves per block
#define RPT 2                                  // rows per lane per wave-tile
#define TROWS (64 * RPT)                       // 128 rows per wave-tile
#define TILE_F (TROWS * ROW_DIM)               // 1408 floats = 5632 B
#define SPROC_STRIDE 12                        // padded proc rows: 16B-aligned ds_read_b128,
                                               // pids spread across banks (~2-way, free)

typedef float v4f __attribute__((ext_vector_type(4)));
typedef int   v2i __attribute__((ext_vector_type(2)));

// Wave-autonomous pipelined gather-concat:
//  - one __syncthreads total (proc-table stage); afterwards each wave runs its own
//    depth-2 software pipeline over 128-row tiles in a private LDS slice
//  - indices prefetched 2 tiles ahead (NT, contiguous), gathers for tile i+1 issued
//    before staging/storing tile i -> scattered-gather latency hides under store drain
//  - stores are full-line wave-coalesced dwordx4 NT from LDS (round-1 lesson:
//    scattered 16B NT stores caused 3.5x write amplification + RMW fetch)
__global__ __launch_bounds__(BLOCK) void gather_concat_kernel(
    const float* __restrict__ proc_pos,     // [16, 8]
    const float* __restrict__ locs_sp,      // [500000, 3]
    const int*   __restrict__ process_ids,  // [NAUG]
    const int*   __restrict__ location_ids, // [NAUG]
    float* __restrict__ out,                // [NAUG, 11]
    int naug)
{
    __shared__ float sproc[NUM_PROCS * SPROC_STRIDE];   // 768 B
    __shared__ float stage[WAVES_PB][TILE_F];           // 22528 B -> 7 blocks/CU (28 waves)

    const int t    = threadIdx.x;
    const int wv   = t >> 6;
    const int lane = t & 63;

    if (t < NUM_PROCS * PROC_DIM)
        sproc[(t >> 3) * SPROC_STRIDE + (t & 7)] = proc_pos[t];
    __syncthreads();    // only barrier; waves are independent after this

    const int WT = naug / TROWS;                    // full wave-tiles (62500 at 8M)
    const int gw = blockIdx.x * WAVES_PB + wv;      // global wave id
    const int NW = gridDim.x * WAVES_PB;            // wave-tile stride (balanced interleave)

    float* const sl      = stage[wv];
    const v4f* const s4  = (const v4f*)sl;

    // ---------------- pipeline prologue ----------------
    v2i pidC = {0, 0}, lidC = {0, 0};   // indices for current tile
    v2i pidN = {0, 0}, lidN = {0, 0};   // indices for next tile
    float ca0=0, ca1=0, ca2=0, cb0=0, cb1=0, cb2=0;   // gather results, current tile

    const int wt0 = gw;
    const int wt1 = gw + NW;
    if (wt0 < WT) {
        pidC = __builtin_nontemporal_load((const v2i*)(process_ids + (size_t)wt0 * TROWS) + lane);
        lidC = __builtin_nontemporal_load((const v2i*)(location_ids + (size_t)wt0 * TROWS) + lane);
    }
    if (wt1 < WT) {
        pidN = __builtin_nontemporal_load((const v2i*)(process_ids + (size_t)wt1 * TROWS) + lane);
        lidN = __builtin_nontemporal_load((const v2i*)(location_ids + (size_t)wt1 * TROWS) + lane);
    }
    if (wt0 < WT) {   // gathers for tile 0 (one unavoidable idx->gather stall, amortized)
        const float* l0 = locs_sp + (size_t)lidC.x * SPATIAL_DIM;
        const float* l1 = locs_sp + (size_t)lidC.y * SPATIAL_DIM;
        ca0 = l0[0]; ca1 = l0[1]; ca2 = l0[2];
        cb0 = l1[0]; cb1 = l1[1]; cb2 = l1[2];
    }

    // ---------------- steady-state loop ----------------
    for (int wt = wt0; wt < WT; wt += NW) {
        const int wtn  = wt + NW;
        const int wtnn = wt + 2 * NW;

        // issue index loads 2 tiles ahead (contiguous 512 B/wave, NT: streamed once)
        v2i pidT = {0, 0}, lidT = {0, 0};
        if (wtnn < WT) {
            pidT = __builtin_nontemporal_load((const v2i*)(process_ids + (size_t)wtnn * TROWS) + lane);
            lidT = __builtin_nontemporal_load((const v2i*)(location_ids + (size_t)wtnn * TROWS) + lane);
        }

        // issue gathers for NEXT tile now: they stay in flight across this tile's
        // LDS staging + store drain (the whole point of the pipeline)
        float na0=0, na1=0, na2=0, nb0=0, nb1=0, nb2=0;
        if (wtn < WT) {
            const float* l0 = locs_sp + (size_t)lidN.x * SPATIAL_DIM;
            const float* l1 = locs_sp + (size_t)lidN.y * SPATIAL_DIM;
            na0 = l0[0]; na1 = l0[1]; na2 = l0[2];
            nb0 = l1[0]; nb1 = l1[1]; nb2 = l1[2];
        }

        // stage current tile into the wave-private slice: rows 2*lane, 2*lane+1
        const v4f* P0 = (const v4f*)(sproc + pidC.x * SPROC_STRIDE);
        const v4f* P1 = (const v4f*)(sproc + pidC.y * SPROC_STRIDE);
        v4f p00 = P0[0], p01 = P0[1];
        v4f p10 = P1[0], p11 = P1[1];
        float* d0 = sl + (size_t)(2 * lane) * ROW_DIM;
        d0[0] = p00.x; d0[1] = p00.y; d0[2]  = p00.z; d0[3] = p00.w;
        d0[4] = p01.x; d0[5] = p01.y; d0[6]  = p01.z; d0[7] = p01.w;
        d0[8] = ca0;   d0[9] = ca1;   d0[10] = ca2;
        float* d1 = d0 + ROW_DIM;
        d1[0] = p10.x; d1[1] = p10.y; d1[2]  = p10.z; d1[3] = p10.w;
        d1[4] = p11.x; d1[5] = p11.y; d1[6]  = p11.z; d1[7] = p11.w;
        d1[8] = cb0;   d1[9] = cb1;   d1[10] = cb2;

        // coalesced NT store: 352 v4f per tile, 1024 B contiguous per wave-instruction.
        // Same-wave DS ops execute in order; compiler inserts the lgkmcnt before reads.
        v4f* out4 = (v4f*)(out + (size_t)wt * TILE_F);
        #pragma unroll
        for (int k = 0; k < 5; ++k) {
            const int i = lane + k * 64;
            __builtin_nontemporal_store(s4[i], out4 + i);
        }
        if (lane < 32) {
            const int i = 320 + lane;
            __builtin_nontemporal_store(s4[i], out4 + i);
        }

        // rotate pipeline registers (all statically named -> pure renaming, no scratch)
        pidC = pidN; lidC = lidN; pidN = pidT; lidN = lidT;
        ca0 = na0; ca1 = na1; ca2 = na2;
        cb0 = nb0; cb1 = nb1; cb2 = nb2;
    }

    // scalar cleanup for naug % TROWS (empty at NAUG = 8M)
    const int tail0 = WT * TROWS;
    if (gw == 0) {
        for (int r = tail0 + lane; r < naug; r += 64) {
            const int pid = process_ids[r];
            const int lid = location_ids[r];
            const float* ps = sproc + pid * SPROC_STRIDE;
            const float* ls = locs_sp + (size_t)lid * SPATIAL_DIM;
            float* orow = out + (size_t)r * ROW_DIM;
            #pragma unroll
            for (int j = 0; j < PROC_DIM; ++j) orow[j] = ps[j];
            orow[8] = ls[0]; orow[9] = ls[1]; orow[10] = ls[2];
        }
    }
}

extern "C" void kernel_launch(void* const* d_in, const int* in_sizes, int n_in,
                              void* d_out, int out_size, void* d_ws, size_t ws_size,
                              hipStream_t stream) {
    const float* proc_pos     = (const float*)d_in[0];
    const float* locs_sp      = (const float*)d_in[1];
    const int*   process_ids  = (const int*)d_in[2];
    const int*   location_ids = (const int*)d_in[3];
    float* out = (float*)d_out;

    const int naug = in_sizes[2];   // 8,000,000
    const int WT   = naug / TROWS;  // 62500 wave-tiles

    // 7 resident blocks/CU (22.5 KB LDS) x 256 CUs = 1792 blocks; each wave then
    // iterates ~8-9 tiles, which is what amortizes the pipeline prologue.
    int grid = 1792;
    if (grid * WAVES_PB > WT) grid = (WT + WAVES_PB - 1) / WAVES_PB;  // small-N fallback
    if (grid < 1) grid = 1;                                           // tail-only case

    gather_concat_kernel<<<grid, BLOCK, 0, stream>>>(
        proc_pos, locs_sp, process_ids, location_ids, out, naug);
}